// Round 12
// baseline (197.280 us; speedup 1.0000x reference)
//
#include <hip/hip_runtime.h>
#include <hip/hip_bf16.h>

#define CC 64
#define HH 128
#define WW 128
#define OO 576   // C * K * K
#define HW (HH * WW)

typedef __attribute__((ext_vector_type(8))) short short8;
typedef __attribute__((ext_vector_type(4))) short short4v;
typedef __attribute__((ext_vector_type(4))) float floatx4;

__device__ __forceinline__ unsigned short f2bf(float f) {
    unsigned u = __float_as_uint(f);
    u = (u + 0x7FFFu + ((u >> 16) & 1u)) >> 16;   // RTNE
    return (unsigned short)u;
}

__device__ __forceinline__ float bf2f(short s) {
    return __uint_as_float(((unsigned)(unsigned short)s) << 16);
}

__device__ __forceinline__ short8 pack8(floatx4 a, floatx4 b) {
    __hip_bfloat162 p0 = __float22bfloat162_rn(make_float2(a[0], a[1]));
    __hip_bfloat162 p1 = __float22bfloat162_rn(make_float2(a[2], a[3]));
    __hip_bfloat162 p2 = __float22bfloat162_rn(make_float2(b[0], b[1]));
    __hip_bfloat162 p3 = __float22bfloat162_rn(make_float2(b[2], b[3]));
    unsigned u0, u1, u2, u3;
    __builtin_memcpy(&u0, &p0, 4); __builtin_memcpy(&u1, &p1, 4);
    __builtin_memcpy(&u2, &p2, 4); __builtin_memcpy(&u3, &p3, 4);
    short8 v;
    v[0] = (short)(u0 & 0xffffu); v[1] = (short)(u0 >> 16);
    v[2] = (short)(u1 & 0xffffu); v[3] = (short)(u1 >> 16);
    v[4] = (short)(u2 & 0xffffu); v[5] = (short)(u2 >> 16);
    v[6] = (short)(u3 & 0xffffu); v[7] = (short)(u3 >> 16);
    return v;
}

// Pre-pass: (1) W_gen -> bf16, tap-major (row o' = kk*64 + c); (2) bias
// permuted tap-major f32: Bp[kk*64 + c] = bg[c*9 + kk].
__global__ void ACDA_wconv_kernel(const float* __restrict__ Wg,
                                  const float* __restrict__ bg,
                                  unsigned short* __restrict__ Wb,
                                  float* __restrict__ Bp) {
    int i = blockIdx.x * 256 + threadIdx.x;
    if (i < OO * CC) {
        int o2  = i >> 6;
        int col = i & 63;
        int kk  = o2 >> 6;
        int c   = o2 & 63;
        Wb[i] = f2bf(Wg[(c * 9 + kk) * CC + col]);
    }
    if (i < OO) Bp[i] = bg[(i & 63) * 9 + (i >> 6)];
}

// R11 post-mortem: residency 5 blocks/CU static but only ~3 waves/SIMD
// average (2.7 generations + ramp/tail); VGPR=44 waves are ~90% latency-
// stalled and TLP never materialized. THIS ROUND: topology, not schedule.
// Block = 512 threads (8 waves) = 2 adjacent h-rows x 4 c-groups sharing a
// 4-row slab (adjacent rows share 2/3 halo rows). LDS 38016B -> 4 blocks/CU
// x 8 waves = 32 waves/CU = 100% ceiling (VGPR<=64: natural was 44).
// Grid 1024 = EXACTLY one generation (4/CU), zero tail, each XCD = 1 image.
// Per-wave compute identical to R11 -- isolates the TLP variable.
__global__ __launch_bounds__(512, 8) void ACDA_main_kernel(
    const float* __restrict__ x, const unsigned short* __restrict__ Wb,
    const float* __restrict__ Bp, float* __restrict__ out)
{
    // S[r][s][c]: r = slab row (x row h0+r-1; zeroed if OOB), s = col slot
    // (0 = left halo, 1..64 = w0..w0+63, 65 = right halo; zeroed at edge),
    // c = channel, padded 64->72 (row stride 144B: 16B-aligned, bank
    // stride 4 -> b128/b64 phases at the structural minimum).
    __shared__ short S[4][66][72];   // 38016 B -> 4 blocks/CU

    const int tid  = threadIdx.x;
    const int lane = tid & 63;
    const int g    = tid >> 6;       // wave 0..7
    const int hw   = g & 1;          // which of the 2 h-rows
    const int cg   = g >> 1;         // 16-channel group 0..3
    const int quad = lane >> 4;
    const int l16  = lane & 15;
    const int c0   = cg * 16;

    // Bijective XCD swizzle: 1024 blocks, 128/XCD = one image per XCD.
    const int bid = blockIdx.x;
    const int wk  = (bid & 7) * 128 + (bid >> 3);
    const int seg = wk & 1;
    const int hp  = (wk >> 1) & 63;
    const int b   = wk >> 7;
    const int w0  = seg << 6;
    const int h0  = hp << 1;         // this block: output rows h0, h0+1

    const float* xb = x + (size_t)b * CC * HW;

    // ---- cooperative slab staging (bf16, zero-filled OOB) ----
    // Slab row r staged by all 8 waves: wave g packs channels g*8..g*8+7,
    // lane = col. 8 coalesced f32 loads + pack8 + one ds_write_b128 per r.
#pragma unroll
    for (int r = 0; r < 4; ++r) {
        const int hh = h0 + r - 1;
        const bool oob = (hh < 0) || (hh > 127);     // block-uniform
        const int hc = hh < 0 ? 0 : (hh > 127 ? 127 : hh);
        const float* src = xb + hc * WW + w0 + lane;
        const int c = g * 8;
        short8 v8 = short8{0, 0, 0, 0, 0, 0, 0, 0};
        if (!oob) {
            floatx4 va, vb;
            va[0] = src[(c + 0) * HW]; va[1] = src[(c + 1) * HW];
            va[2] = src[(c + 2) * HW]; va[3] = src[(c + 3) * HW];
            vb[0] = src[(c + 4) * HW]; vb[1] = src[(c + 5) * HW];
            vb[2] = src[(c + 6) * HW]; vb[3] = src[(c + 7) * HW];
            v8 = pack8(va, vb);
        }
        *(short8*)&S[r][lane + 1][c] = v8;
    }
    {   // halo cols: 512 slots = 4 rows x 64 ch x 2 sides, one per thread
        const int r4   = tid >> 7;          // slab row 0..3
        const int idx  = tid & 127;
        const int c    = idx >> 1;
        const int side = idx & 1;
        const int hh = h0 + r4 - 1;
        const bool oob = (hh < 0) || (hh > 127);
        const int hc = hh < 0 ? 0 : (hh > 127 ? 127 : hh);
        const int col = side ? (w0 + 64) : (w0 - 1);
        unsigned short v = 0;
        if (!oob && col >= 0 && col < WW)
            v = f2bf(xb[c * HW + hc * WW + col]);
        S[r4][side ? 65 : 0][c] = (short)v;
    }
    __syncthreads();   // the ONLY barrier; S read-only afterwards

    // ---- B fragments: direct short8 ds_read from slab row hw+1 ----
    short8 bfrag[4][2];
#pragma unroll
    for (int nt = 0; nt < 4; ++nt)
#pragma unroll
        for (int ks = 0; ks < 2; ++ks)
            bfrag[nt][ks] = *(const short8*)&S[hw + 1][nt * 16 + l16 + 1][ks * 32 + quad * 8];

    // Output accumulator in MFMA layout: acc[nt][rg] <-> channel
    // c0+4*quad+rg, pixel (h0+hw, w0+16*nt+l16).
    floatx4 acc[4];
#pragma unroll
    for (int nt = 0; nt < 4; ++nt) acc[nt] = floatx4{0.f, 0.f, 0.f, 0.f};

    // ---- 9 taps, fully unrolled. Per tap: A 2xb128 + bias b128 (L1-hot);
    // 4x ds_read_b64 patches; 8 MFMA (bias as acc-init); 16 relu-FMA.
#pragma unroll
    for (int t = 0; t < 9; ++t) {
        const int di = t / 3;
        const int dj = t - 3 * di;
        const unsigned short* wrow = Wb + (t * 64 + c0 + l16) * CC + quad * 8;
        short8 a0 = *(const short8*)(wrow);
        short8 a1 = *(const short8*)(wrow + 32);
        floatx4 bv = *(const floatx4*)(Bp + t * 64 + c0 + 4 * quad);
#pragma unroll
        for (int nt = 0; nt < 4; ++nt) {
            short4v ph = *(const short4v*)&S[hw + di][nt * 16 + l16 + dj][c0 + 4 * quad];
            floatx4 z = bv;   // bias pre-ReLU as accumulator init
            z = __builtin_amdgcn_mfma_f32_16x16x32_bf16(a0, bfrag[nt][0], z, 0, 0, 0);
            z = __builtin_amdgcn_mfma_f32_16x16x32_bf16(a1, bfrag[nt][1], z, 0, 0, 0);
#pragma unroll
            for (int rg = 0; rg < 4; ++rg)
                acc[nt][rg] = fmaf(fmaxf(z[rg], 0.f), bf2f(ph[rg]), acc[nt][rg]);
        }
    }

    // ---- epilogue: stores directly from MFMA-layout acc ----
    float* ob = out + (size_t)b * CC * HW + (h0 + hw) * WW + w0;
#pragma unroll
    for (int nt = 0; nt < 4; ++nt)
#pragma unroll
        for (int rg = 0; rg < 4; ++rg)
            ob[(c0 + 4 * quad + rg) * HW + nt * 16 + l16] = acc[nt][rg];
}

extern "C" void kernel_launch(void* const* d_in, const int* in_sizes, int n_in,
                              void* d_out, int out_size, void* d_ws, size_t ws_size,
                              hipStream_t stream) {
    const float* x  = (const float*)d_in[0];
    const float* Wg = (const float*)d_in[1];
    const float* bg = (const float*)d_in[2];
    float* out = (float*)d_out;
    unsigned short* Wb = (unsigned short*)d_ws;            // 73728 B
    float* Bp = (float*)((char*)d_ws + OO * CC * 2);       // + 2304 B

    ACDA_wconv_kernel<<<dim3((OO * CC + 255) / 256), dim3(256), 0, stream>>>(Wg, bg, Wb, Bp);
    ACDA_main_kernel<<<dim3(8 * 64 * 2), dim3(512), 0, stream>>>(x, Wb, Bp, out);
}

// Round 13
// 153.240 us; speedup vs baseline: 1.2874x; 1.2874x over previous
//
#include <hip/hip_runtime.h>
#include <hip/hip_bf16.h>

#define CC 64
#define HH 128
#define WW 128
#define OO 576   // C * K * K
#define HW (HH * WW)

typedef __attribute__((ext_vector_type(8))) short short8;
typedef __attribute__((ext_vector_type(4))) short short4v;
typedef __attribute__((ext_vector_type(4))) float floatx4;

__device__ __forceinline__ unsigned short f2bf(float f) {
    unsigned u = __float_as_uint(f);
    u = (u + 0x7FFFu + ((u >> 16) & 1u)) >> 16;   // RTNE
    return (unsigned short)u;
}

__device__ __forceinline__ float bf2f(short s) {
    return __uint_as_float(((unsigned)(unsigned short)s) << 16);
}

__device__ __forceinline__ short8 pack8(floatx4 a, floatx4 b) {
    __hip_bfloat162 p0 = __float22bfloat162_rn(make_float2(a[0], a[1]));
    __hip_bfloat162 p1 = __float22bfloat162_rn(make_float2(a[2], a[3]));
    __hip_bfloat162 p2 = __float22bfloat162_rn(make_float2(b[0], b[1]));
    __hip_bfloat162 p3 = __float22bfloat162_rn(make_float2(b[2], b[3]));
    unsigned u0, u1, u2, u3;
    __builtin_memcpy(&u0, &p0, 4); __builtin_memcpy(&u1, &p1, 4);
    __builtin_memcpy(&u2, &p2, 4); __builtin_memcpy(&u3, &p3, 4);
    short8 v;
    v[0] = (short)(u0 & 0xffffu); v[1] = (short)(u0 >> 16);
    v[2] = (short)(u1 & 0xffffu); v[3] = (short)(u1 >> 16);
    v[4] = (short)(u2 & 0xffffu); v[5] = (short)(u2 >> 16);
    v[6] = (short)(u3 & 0xffffu); v[7] = (short)(u3 >> 16);
    return v;
}

// Pre-pass: (1) W_gen -> bf16, tap-major (row o' = kk*64 + c); (2) bias
// permuted tap-major f32: Bp[kk*64 + c] = bg[c*9 + kk].
__global__ void ACDA_wconv_kernel(const float* __restrict__ Wg,
                                  const float* __restrict__ bg,
                                  unsigned short* __restrict__ Wb,
                                  float* __restrict__ Bp) {
    int i = blockIdx.x * 256 + threadIdx.x;
    if (i < OO * CC) {
        int o2  = i >> 6;
        int col = i & 63;
        int kk  = o2 >> 6;
        int c   = o2 & 63;
        Wb[i] = f2bf(Wg[(c * 9 + kk) * CC + col]);
    }
    if (i < OO) Bp[i] = bg[(i & 63) * 9 + (i >> 6)];
}

// R12 post-mortem: the 8-wave/2-row topology DID deliver occupancy (67%,
// highest ever) but __launch_bounds__(512,8) capped the unified file at 64
// regs and the allocator split arch/acc -> VGPR=32 -> spill (WRITE 181MB,
// FETCH 205MB) -- R1's failure mode repeated. ONE-NUMBER FIX: (512,6) caps
// at 85 (natural need ~60 total = 44 arch + 16 acc). The declared min only
// constrains the ALLOCATOR; if it lands at <=64 naturally, hardware still
// fits 8 waves/SIMD (LDS 38KB -> 4 blocks/CU = 32 waves/CU ceiling).
__global__ __launch_bounds__(512, 6) void ACDA_main_kernel(
    const float* __restrict__ x, const unsigned short* __restrict__ Wb,
    const float* __restrict__ Bp, float* __restrict__ out)
{
    // S[r][s][c]: r = slab row (x row h0+r-1; zeroed if OOB), s = col slot
    // (0 = left halo, 1..64 = w0..w0+63, 65 = right halo; zeroed at edge),
    // c = channel, padded 64->72 (row stride 144B: 16B-aligned, bank
    // stride 4 -> b128/b64 phases at the structural minimum).
    __shared__ short S[4][66][72];   // 38016 B -> 4 blocks/CU

    const int tid  = threadIdx.x;
    const int lane = tid & 63;
    const int g    = tid >> 6;       // wave 0..7
    const int hw   = g & 1;          // which of the 2 h-rows
    const int cg   = g >> 1;         // 16-channel group 0..3
    const int quad = lane >> 4;
    const int l16  = lane & 15;
    const int c0   = cg * 16;

    // Bijective XCD swizzle: 1024 blocks, 128/XCD = one image per XCD.
    const int bid = blockIdx.x;
    const int wk  = (bid & 7) * 128 + (bid >> 3);
    const int seg = wk & 1;
    const int hp  = (wk >> 1) & 63;
    const int b   = wk >> 7;
    const int w0  = seg << 6;
    const int h0  = hp << 1;         // this block: output rows h0, h0+1

    const float* xb = x + (size_t)b * CC * HW;

    // ---- cooperative slab staging (bf16, zero-filled OOB) ----
    // Slab row r staged by all 8 waves: wave g packs channels g*8..g*8+7,
    // lane = col. 8 coalesced f32 loads + pack8 + one ds_write_b128 per r.
#pragma unroll
    for (int r = 0; r < 4; ++r) {
        const int hh = h0 + r - 1;
        const bool oob = (hh < 0) || (hh > 127);     // block-uniform
        const int hc = hh < 0 ? 0 : (hh > 127 ? 127 : hh);
        const float* src = xb + hc * WW + w0 + lane;
        const int c = g * 8;
        short8 v8 = short8{0, 0, 0, 0, 0, 0, 0, 0};
        if (!oob) {
            floatx4 va, vb;
            va[0] = src[(c + 0) * HW]; va[1] = src[(c + 1) * HW];
            va[2] = src[(c + 2) * HW]; va[3] = src[(c + 3) * HW];
            vb[0] = src[(c + 4) * HW]; vb[1] = src[(c + 5) * HW];
            vb[2] = src[(c + 6) * HW]; vb[3] = src[(c + 7) * HW];
            v8 = pack8(va, vb);
        }
        *(short8*)&S[r][lane + 1][c] = v8;
    }
    {   // halo cols: 512 slots = 4 rows x 64 ch x 2 sides, one per thread
        const int r4   = tid >> 7;          // slab row 0..3
        const int idx  = tid & 127;
        const int c    = idx >> 1;
        const int side = idx & 1;
        const int hh = h0 + r4 - 1;
        const bool oob = (hh < 0) || (hh > 127);
        const int hc = hh < 0 ? 0 : (hh > 127 ? 127 : hh);
        const int col = side ? (w0 + 64) : (w0 - 1);
        unsigned short v = 0;
        if (!oob && col >= 0 && col < WW)
            v = f2bf(xb[c * HW + hc * WW + col]);
        S[r4][side ? 65 : 0][c] = (short)v;
    }
    __syncthreads();   // the ONLY barrier; S read-only afterwards

    // ---- B fragments: direct short8 ds_read from slab row hw+1 ----
    short8 bfrag[4][2];
#pragma unroll
    for (int nt = 0; nt < 4; ++nt)
#pragma unroll
        for (int ks = 0; ks < 2; ++ks)
            bfrag[nt][ks] = *(const short8*)&S[hw + 1][nt * 16 + l16 + 1][ks * 32 + quad * 8];

    // Output accumulator in MFMA layout: acc[nt][rg] <-> channel
    // c0+4*quad+rg, pixel (h0+hw, w0+16*nt+l16).
    floatx4 acc[4];
#pragma unroll
    for (int nt = 0; nt < 4; ++nt) acc[nt] = floatx4{0.f, 0.f, 0.f, 0.f};

    // ---- 9 taps, fully unrolled. Per tap: A 2xb128 + bias b128 (L1-hot);
    // 4x ds_read_b64 patches; 8 MFMA (bias as acc-init); 16 relu-FMA.
#pragma unroll
    for (int t = 0; t < 9; ++t) {
        const int di = t / 3;
        const int dj = t - 3 * di;
        const unsigned short* wrow = Wb + (t * 64 + c0 + l16) * CC + quad * 8;
        short8 a0 = *(const short8*)(wrow);
        short8 a1 = *(const short8*)(wrow + 32);
        floatx4 bv = *(const floatx4*)(Bp + t * 64 + c0 + 4 * quad);
#pragma unroll
        for (int nt = 0; nt < 4; ++nt) {
            short4v ph = *(const short4v*)&S[hw + di][nt * 16 + l16 + dj][c0 + 4 * quad];
            floatx4 z = bv;   // bias pre-ReLU as accumulator init
            z = __builtin_amdgcn_mfma_f32_16x16x32_bf16(a0, bfrag[nt][0], z, 0, 0, 0);
            z = __builtin_amdgcn_mfma_f32_16x16x32_bf16(a1, bfrag[nt][1], z, 0, 0, 0);
#pragma unroll
            for (int rg = 0; rg < 4; ++rg)
                acc[nt][rg] = fmaf(fmaxf(z[rg], 0.f), bf2f(ph[rg]), acc[nt][rg]);
        }
    }

    // ---- epilogue: stores directly from MFMA-layout acc ----
    float* ob = out + (size_t)b * CC * HW + (h0 + hw) * WW + w0;
#pragma unroll
    for (int nt = 0; nt < 4; ++nt)
#pragma unroll
        for (int rg = 0; rg < 4; ++rg)
            ob[(c0 + 4 * quad + rg) * HW + nt * 16 + l16] = acc[nt][rg];
}

extern "C" void kernel_launch(void* const* d_in, const int* in_sizes, int n_in,
                              void* d_out, int out_size, void* d_ws, size_t ws_size,
                              hipStream_t stream) {
    const float* x  = (const float*)d_in[0];
    const float* Wg = (const float*)d_in[1];
    const float* bg = (const float*)d_in[2];
    float* out = (float*)d_out;
    unsigned short* Wb = (unsigned short*)d_ws;            // 73728 B
    float* Bp = (float*)((char*)d_ws + OO * CC * 2);       // + 2304 B

    ACDA_wconv_kernel<<<dim3((OO * CC + 255) / 256), dim3(256), 0, stream>>>(Wg, bg, Wb, Bp);
    ACDA_main_kernel<<<dim3(8 * 64 * 2), dim3(512), 0, stream>>>(x, Wb, Bp, out);
}

// Round 14
// 106.860 us; speedup vs baseline: 1.8462x; 1.4340x over previous
//
#include <hip/hip_runtime.h>
#include <hip/hip_bf16.h>

#define CC 64
#define HH 128
#define WW 128
#define OO 576   // C * K * K
#define HW (HH * WW)

typedef __attribute__((ext_vector_type(8))) short short8;
typedef __attribute__((ext_vector_type(4))) short short4v;
typedef __attribute__((ext_vector_type(4))) float floatx4;

__device__ __forceinline__ unsigned short f2bf(float f) {
    unsigned u = __float_as_uint(f);
    u = (u + 0x7FFFu + ((u >> 16) & 1u)) >> 16;   // RTNE
    return (unsigned short)u;
}

__device__ __forceinline__ float bf2f(short s) {
    return __uint_as_float(((unsigned)(unsigned short)s) << 16);
}

__device__ __forceinline__ short8 pack8(floatx4 a, floatx4 b) {
    __hip_bfloat162 p0 = __float22bfloat162_rn(make_float2(a[0], a[1]));
    __hip_bfloat162 p1 = __float22bfloat162_rn(make_float2(a[2], a[3]));
    __hip_bfloat162 p2 = __float22bfloat162_rn(make_float2(b[0], b[1]));
    __hip_bfloat162 p3 = __float22bfloat162_rn(make_float2(b[2], b[3]));
    unsigned u0, u1, u2, u3;
    __builtin_memcpy(&u0, &p0, 4); __builtin_memcpy(&u1, &p1, 4);
    __builtin_memcpy(&u2, &p2, 4); __builtin_memcpy(&u3, &p3, 4);
    short8 v;
    v[0] = (short)(u0 & 0xffffu); v[1] = (short)(u0 >> 16);
    v[2] = (short)(u1 & 0xffffu); v[3] = (short)(u1 >> 16);
    v[4] = (short)(u2 & 0xffffu); v[5] = (short)(u2 >> 16);
    v[6] = (short)(u3 & 0xffffu); v[7] = (short)(u3 >> 16);
    return v;
}

// Pre-pass: (1) W_gen -> bf16, tap-major (row o' = kk*64 + c); (2) bias
// permuted tap-major f32: Bp[kk*64 + c] = bg[c*9 + kk].
__global__ void ACDA_wconv_kernel(const float* __restrict__ Wg,
                                  const float* __restrict__ bg,
                                  unsigned short* __restrict__ Wb,
                                  float* __restrict__ Bp) {
    int i = blockIdx.x * 256 + threadIdx.x;
    if (i < OO * CC) {
        int o2  = i >> 6;
        int col = i & 63;
        int kk  = o2 >> 6;
        int c   = o2 & 63;
        Wb[i] = f2bf(Wg[(c * 9 + kk) * CC + col]);
    }
    if (i < OO) Bp[i] = bg[(i & 63) * 9 + (i >> 6)];
}

// R13 post-mortem: launch-bounds cap splits the unified reg file ~50:50
// arch/accum (cap 64 -> arch 32 [R12]; cap 85 -> arch 40 [R13]); this
// kernel needs ~44 arch (bfrag 32 + addr) + 16 acc, so arch 40 still
// spilled (WRITE 135MB). Occupancy 52% at dur 81us PROVES the topology
// works; the spill is the last poison. Fix: (512,4) -> budget 128 ->
// arch ~64 >= 44, no spill. Min-waves 4 (16/CU) is below the LDS limit
// (4 blocks x 8 waves = 32/CU), so it constrains only the allocator.
__global__ __launch_bounds__(512, 4) void ACDA_main_kernel(
    const float* __restrict__ x, const unsigned short* __restrict__ Wb,
    const float* __restrict__ Bp, float* __restrict__ out)
{
    // S[r][s][c]: r = slab row (x row h0+r-1; zeroed if OOB), s = col slot
    // (0 = left halo, 1..64 = w0..w0+63, 65 = right halo; zeroed at edge),
    // c = channel, padded 64->72 (row stride 144B: 16B-aligned, bank
    // stride 4 -> b128/b64 phases at the structural minimum).
    __shared__ short S[4][66][72];   // 38016 B -> 4 blocks/CU

    const int tid  = threadIdx.x;
    const int lane = tid & 63;
    const int g    = tid >> 6;       // wave 0..7
    const int hw   = g & 1;          // which of the 2 h-rows
    const int cg   = g >> 1;         // 16-channel group 0..3
    const int quad = lane >> 4;
    const int l16  = lane & 15;
    const int c0   = cg * 16;

    // Bijective XCD swizzle: 1024 blocks, 128/XCD = one image per XCD.
    const int bid = blockIdx.x;
    const int wk  = (bid & 7) * 128 + (bid >> 3);
    const int seg = wk & 1;
    const int hp  = (wk >> 1) & 63;
    const int b   = wk >> 7;
    const int w0  = seg << 6;
    const int h0  = hp << 1;         // this block: output rows h0, h0+1

    const float* xb = x + (size_t)b * CC * HW;

    // ---- cooperative slab staging (bf16, zero-filled OOB) ----
    // Slab row r staged by all 8 waves: wave g packs channels g*8..g*8+7,
    // lane = col. 8 coalesced f32 loads + pack8 + one ds_write_b128 per r.
#pragma unroll
    for (int r = 0; r < 4; ++r) {
        const int hh = h0 + r - 1;
        const bool oob = (hh < 0) || (hh > 127);     // block-uniform
        const int hc = hh < 0 ? 0 : (hh > 127 ? 127 : hh);
        const float* src = xb + hc * WW + w0 + lane;
        const int c = g * 8;
        short8 v8 = short8{0, 0, 0, 0, 0, 0, 0, 0};
        if (!oob) {
            floatx4 va, vb;
            va[0] = src[(c + 0) * HW]; va[1] = src[(c + 1) * HW];
            va[2] = src[(c + 2) * HW]; va[3] = src[(c + 3) * HW];
            vb[0] = src[(c + 4) * HW]; vb[1] = src[(c + 5) * HW];
            vb[2] = src[(c + 6) * HW]; vb[3] = src[(c + 7) * HW];
            v8 = pack8(va, vb);
        }
        *(short8*)&S[r][lane + 1][c] = v8;
    }
    {   // halo cols: 512 slots = 4 rows x 64 ch x 2 sides, one per thread
        const int r4   = tid >> 7;          // slab row 0..3
        const int idx  = tid & 127;
        const int c    = idx >> 1;
        const int side = idx & 1;
        const int hh = h0 + r4 - 1;
        const bool oob = (hh < 0) || (hh > 127);
        const int hc = hh < 0 ? 0 : (hh > 127 ? 127 : hh);
        const int col = side ? (w0 + 64) : (w0 - 1);
        unsigned short v = 0;
        if (!oob && col >= 0 && col < WW)
            v = f2bf(xb[c * HW + hc * WW + col]);
        S[r4][side ? 65 : 0][c] = (short)v;
    }
    __syncthreads();   // the ONLY barrier; S read-only afterwards

    // ---- B fragments: direct short8 ds_read from slab row hw+1 ----
    short8 bfrag[4][2];
#pragma unroll
    for (int nt = 0; nt < 4; ++nt)
#pragma unroll
        for (int ks = 0; ks < 2; ++ks)
            bfrag[nt][ks] = *(const short8*)&S[hw + 1][nt * 16 + l16 + 1][ks * 32 + quad * 8];

    // Output accumulator in MFMA layout: acc[nt][rg] <-> channel
    // c0+4*quad+rg, pixel (h0+hw, w0+16*nt+l16).
    floatx4 acc[4];
#pragma unroll
    for (int nt = 0; nt < 4; ++nt) acc[nt] = floatx4{0.f, 0.f, 0.f, 0.f};

    // ---- 9 taps, fully unrolled. Per tap: A 2xb128 + bias b128 (L1-hot);
    // 4x ds_read_b64 patches; 8 MFMA (bias as acc-init); 16 relu-FMA.
#pragma unroll
    for (int t = 0; t < 9; ++t) {
        const int di = t / 3;
        const int dj = t - 3 * di;
        const unsigned short* wrow = Wb + (t * 64 + c0 + l16) * CC + quad * 8;
        short8 a0 = *(const short8*)(wrow);
        short8 a1 = *(const short8*)(wrow + 32);
        floatx4 bv = *(const floatx4*)(Bp + t * 64 + c0 + 4 * quad);
#pragma unroll
        for (int nt = 0; nt < 4; ++nt) {
            short4v ph = *(const short4v*)&S[hw + di][nt * 16 + l16 + dj][c0 + 4 * quad];
            floatx4 z = bv;   // bias pre-ReLU as accumulator init
            z = __builtin_amdgcn_mfma_f32_16x16x32_bf16(a0, bfrag[nt][0], z, 0, 0, 0);
            z = __builtin_amdgcn_mfma_f32_16x16x32_bf16(a1, bfrag[nt][1], z, 0, 0, 0);
#pragma unroll
            for (int rg = 0; rg < 4; ++rg)
                acc[nt][rg] = fmaf(fmaxf(z[rg], 0.f), bf2f(ph[rg]), acc[nt][rg]);
        }
    }

    // ---- epilogue: stores directly from MFMA-layout acc ----
    float* ob = out + (size_t)b * CC * HW + (h0 + hw) * WW + w0;
#pragma unroll
    for (int nt = 0; nt < 4; ++nt)
#pragma unroll
        for (int rg = 0; rg < 4; ++rg)
            ob[(c0 + 4 * quad + rg) * HW + nt * 16 + l16] = acc[nt][rg];
}

extern "C" void kernel_launch(void* const* d_in, const int* in_sizes, int n_in,
                              void* d_out, int out_size, void* d_ws, size_t ws_size,
                              hipStream_t stream) {
    const float* x  = (const float*)d_in[0];
    const float* Wg = (const float*)d_in[1];
    const float* bg = (const float*)d_in[2];
    float* out = (float*)d_out;
    unsigned short* Wb = (unsigned short*)d_ws;            // 73728 B
    float* Bp = (float*)((char*)d_ws + OO * CC * 2);       // + 2304 B

    ACDA_wconv_kernel<<<dim3((OO * CC + 255) / 256), dim3(256), 0, stream>>>(Wg, bg, Wb, Bp);
    ACDA_main_kernel<<<dim3(8 * 64 * 2), dim3(512), 0, stream>>>(x, Wb, Bp, out);
}